// Round 4
// baseline (139.066 us; speedup 1.0000x reference)
//
#include <hip/hip_runtime.h>

// LIF scan: z [B=32, T=1024, H=512] fp32 -> out [32,1024,512] fp32
//   V_t = 0.9*V_{t-1} + z[:,t-1,:] - (V_{t-1} > 1)      (exact fp32 op order)
//   out[:,t,:] = (V_t > 1) ? 1 : 0,  out[:,0,:] = 0
//
// 256 blocks x 64 threads (1 wave/CU); thread = one (b,h) chain.
// R1/R3 lesson: register-resident VMEM prefetch pipelines get dissolved by
// the compiler (VGPR 36/48 vs required 70+). R2 lesson: volatile = vmcnt(0)
// per load. This round: global_load_lds DMA double-buffer — the DMA's LDS
// write is un-deletable, uses no VGPRs for data, and completion is gated by
// an explicit s_waitcnt vmcnt(16) that keeps the prefetch chunk in flight.
//
// Chunk = 64 steps = float[64][64] (16 KiB). 16 chunks cover steps 0..1023
// (step 1023 staged but unused; in-bounds). DMA inst j of a chunk: lane i
// fetches 16 B at z[b, c*64 + 4j + (i>>4), h0 + (i&15)*4]; HW writes LDS at
// (base + j*1024) + i*16  ==> row-major [s_local][h_local]. 2-way LDS bank
// alias on read (free).

#define LIF_H 512

typedef __attribute__((address_space(3))) void lds_void_t;
typedef const __attribute__((address_space(1))) void gbl_void_t;
#define DMA16(gp, lp) \
    __builtin_amdgcn_global_load_lds((gbl_void_t*)(gp), (lds_void_t*)(lp), 16, 0, 0)

// s_waitcnt simm16 (gfx9): vmcnt[3:0]=simm[3:0], vmcnt[5:4]=simm[15:14],
// expcnt=simm[6:4], lgkmcnt=simm[11:8].  Don't-care fields set to max.
#define WAIT_VM16() __builtin_amdgcn_s_waitcnt(0x4F70)  // vmcnt <= 16
#define WAIT_VM0()  __builtin_amdgcn_s_waitcnt(0x0F70)  // vmcnt == 0

__global__ __launch_bounds__(64, 1) void lif_kernel(const float* __restrict__ z,
                                                    float* __restrict__ out) {
    __shared__ float bufA[64 * 64];
    __shared__ float bufB[64 * 64];

    const int tid = threadIdx.x;
    const int blk = blockIdx.x;
    const int b = blk >> 3;                      // 8 blocks per batch row
    const int h0 = (blk & 7) << 6;               // 64 h-chains per block
    const size_t base = (size_t)b * (1024 * LIF_H) + h0;

    const float* zb = z + base;                  // z[b, s, h0+.] row s at +s*512
    float* op = out + base + tid;                // out[b, t, h0+tid] at +t*512

    op[0] = 0.0f;                                // t = 0 row stays zero

    // per-lane global source (floats) for DMA inst j of chunk c:
    //   gsrc + c*(64*512) + j*(4*512)
    const float* gsrc = zb + (tid >> 4) * LIF_H + (tid & 15) * 4;

    // stage chunk 0 -> A
#pragma unroll
    for (int j = 0; j < 16; ++j)
        DMA16(gsrc + j * (4 * LIF_H), bufA + j * 256);

    float V = 0.0f;
    for (int p = 0; p < 8; ++p) {
        const int c0 = 2 * p;

        // prefetch chunk c0+1 -> B
#pragma unroll
        for (int j = 0; j < 16; ++j)
            DMA16(gsrc + (size_t)(c0 + 1) * (64 * LIF_H) + j * (4 * LIF_H),
                  bufB + j * 256);
        WAIT_VM16();                             // A complete; B stays in flight

        // compute chunk c0 from A
#pragma unroll 4
        for (int s = 0; s < 64; ++s) {
            const float zv = bufA[s * 64 + tid];
            const float v0 = __fadd_rn(__fmul_rn(0.9f, V), zv);
            const float Vn = (V > 1.0f) ? __fsub_rn(v0, 1.0f) : v0;
            op[(size_t)(c0 * 64 + s + 1) * LIF_H] = (Vn > 1.0f) ? 1.0f : 0.0f;
            V = Vn;
        }

        if (p < 7) {
            // prefetch chunk c0+2 -> A
#pragma unroll
            for (int j = 0; j < 16; ++j)
                DMA16(gsrc + (size_t)(c0 + 2) * (64 * LIF_H) + j * (4 * LIF_H),
                      bufA + j * 256);
            WAIT_VM16();                         // B complete; A stays in flight
        } else {
            WAIT_VM0();                          // last pair: just drain B
        }

        // compute chunk c0+1 from B (last chunk computes 63 steps: t<=1023)
        const int smax = (p < 7) ? 64 : 63;
#pragma unroll 4
        for (int s = 0; s < smax; ++s) {
            const float zv = bufB[s * 64 + tid];
            const float v0 = __fadd_rn(__fmul_rn(0.9f, V), zv);
            const float Vn = (V > 1.0f) ? __fsub_rn(v0, 1.0f) : v0;
            op[(size_t)((c0 + 1) * 64 + s + 1) * LIF_H] = (Vn > 1.0f) ? 1.0f : 0.0f;
            V = Vn;
        }
    }
}

extern "C" void kernel_launch(void* const* d_in, const int* in_sizes, int n_in,
                              void* d_out, int out_size, void* d_ws, size_t ws_size,
                              hipStream_t stream) {
    const float* z = (const float*)d_in[0];
    float* out = (float*)d_out;
    dim3 block(64);
    dim3 grid(256);                              // 32 b-rows x 8 h-slices
    hipLaunchKernelGGL(lif_kernel, grid, block, 0, stream, z, out);
}